// Round 9
// baseline (328.290 us; speedup 1.0000x reference)
//
#include <hip/hip_runtime.h>
#include <math.h>

#define NA 10000
#define NE 40000

typedef float f4 __attribute__((ext_vector_type(4)));
typedef float f16v __attribute__((ext_vector_type(16)));
typedef int   i4 __attribute__((ext_vector_type(4)));
typedef __bf16 bf16x8 __attribute__((ext_vector_type(8)));

union U8 { unsigned short us[8]; bf16x8 v; };

static __device__ __forceinline__ unsigned short bf_rne(float x){
  unsigned u = __float_as_uint(x);
  unsigned r = (u + 0x7fffu + ((u>>16)&1u)) >> 16;
  return (unsigned short)r;
}
static __device__ __forceinline__ float bf_to_f(unsigned short h){
  return __uint_as_float(((unsigned)h)<<16);
}

// ---------------- k_pre: fold BN, build MFMA tables, p[a], histogram ----------------
__global__ __launch_bounds__(256) void k_pre(
  const float* __restrict__ encW, const float* __restrict__ encB,
  const float* __restrict__ eg, const float* __restrict__ ebt,
  const float* __restrict__ e_mn, const float* __restrict__ e_vr,
  const float* __restrict__ attW, const float* __restrict__ attB,
  const float* __restrict__ agm, const float* __restrict__ abt,
  const float* __restrict__ amn, const float* __restrict__ avr,
  const float* __restrict__ wih, const float* __restrict__ whh,
  const int* __restrict__ bidx, const float* __restrict__ atom,
  const float* __restrict__ alW,
  unsigned short* __restrict__ Bh, unsigned short* __restrict__ Bl,
  unsigned short* __restrict__ aBh, unsigned short* __restrict__ aBl,
  float* __restrict__ attBf, float* __restrict__ wT,
  float* __restrict__ p, int* __restrict__ cnt)
{
  int tid = threadIdx.x;
  int gid = blockIdx.x*256 + tid;
  int gstride = gridDim.x*256;
  // enc B-fragments [d(64)][ft(2)][lane(64)][j(8)]
  for (int i=gid; i<65536; i+=gstride){
    int j = i&7, ll = (i>>3)&63, t = i>>9;
    int d = t>>1, ft = t&1;
    int k = ((ll>>5)<<3)+j;
    int n = d*64 + ft*32 + (ll&31);
    float s = eg[n]*rsqrtf(e_vr[n]+1e-6f);
    unsigned short vh=0, vl=0;
    if (k<12){
      float wv = encW[n*12+k]*s;
      unsigned short hi = bf_rne(wv);
      vh = hi; vl = bf_rne(wv - bf_to_f(hi));
    } else if (k==12){
      float b = (encB[n]-e_mn[n])*s + ebt[n];
      unsigned short hi = bf_rne(b);
      vh = hi; vl = bf_rne(b - bf_to_f(hi));
    }
    Bh[i] = vh; Bl[i] = vl;
  }
  // attd B-fragments [kk(4)][nt(2)][lane(64)][j(8)]; B[k][n] = attW[n*64+k]*s_n
  for (int i=gid; i<4096; i+=gstride){
    int j=i&7, l=(i>>3)&63, t=i>>9;
    int kk=t>>1, nt=t&1;
    int k = kk*16 + ((l>>5)<<3) + j;
    int n = nt*32 + (l&31);
    float s = agm[n]*rsqrtf(avr[n]+1e-6f);
    float wv = attW[n*64+k]*s;
    unsigned short hi = bf_rne(wv);
    aBh[i]=hi; aBl[i]=bf_rne(wv - bf_to_f(hi));
  }
  for (int f=gid; f<64; f+=gstride){
    float s = agm[f]*rsqrtf(avr[f]+1e-6f);
    attBf[f] = (attB[f]-amn[f])*s + abt[f];
  }
  // GRU weights [g(6)][kg(16)][f(64)][j(4)]
  for (int i=gid; i<24576; i+=gstride){
    int j=i&3, f=(i>>2)&63, idx2=i>>8;
    int g=idx2>>4, kg=idx2&15, k=kg*4+j;
    wT[i] = (g<3)? wih[(g*64+f)*64+k] : whh[((g-3)*64+f)*64+k];
  }
  // p[a] = alW[0:64] . atom[a]
  {
    int wid = gid>>6;
    int l = tid&63;
    float wl = alW[l];
    for (int a=wid; a<NA; a+=(gstride>>6)){
      float v = wl*atom[(size_t)a*64+l];
      v += __shfl_xor(v,1);  v += __shfl_xor(v,2);
      v += __shfl_xor(v,4);  v += __shfl_xor(v,8);
      v += __shfl_xor(v,16); v += __shfl_xor(v,32);
      if (l==0) p[a]=v;
    }
  }
  for (int e=gid; e<NE; e+=gstride) atomicAdd(&cnt[bidx[e*2]],1);
}

// ---------------- k_scan ----------------
__global__ __launch_bounds__(256) void k_scan(const int* __restrict__ cnt,
                                              int* __restrict__ rowstart,
                                              int* __restrict__ wofs)
{
  __shared__ int sPart[256];
  int t = threadIdx.x;
  int base = t*40;
  i4 buf[10];
  int sum = 0;
  if (base < NA){
    const i4* cp = (const i4*)(cnt + base);
    #pragma unroll
    for (int i=0;i<10;i++) buf[i] = cp[i];
    #pragma unroll
    for (int i=0;i<10;i++) sum += buf[i].x+buf[i].y+buf[i].z+buf[i].w;
  }
  sPart[t]=sum;
  __syncthreads();
  for (int off=1; off<256; off<<=1){
    int v = (t>=off)? sPart[t-off] : 0;
    __syncthreads();
    sPart[t]+=v;
    __syncthreads();
  }
  int run = sPart[t]-sum;
  if (base < NA){
    #pragma unroll
    for (int i=0;i<10;i++){
      i4 b=buf[i], o;
      o.x=run; run+=b.x; o.y=run; run+=b.y;
      o.z=run; run+=b.z; o.w=run; run+=b.w;
      ((i4*)(rowstart+base))[i]=o;
      ((i4*)(wofs+base))[i]=o;
    }
  }
  if (t==0) rowstart[NA]=NE;
}

// ---------------- k_scatter ----------------
__global__ __launch_bounds__(256) void k_scatter(const int* __restrict__ bidx,
                                                 int* __restrict__ wofs,
                                                 int* __restrict__ elist)
{
  int e = blockIdx.x*256 + threadIdx.x;
  if (e < NE){
    int tg = bidx[e*2];
    int pos = atomicAdd(&wofs[tg],1);
    elist[pos]=e;
  }
}

// ---------------- k_edge: MFMA enc GEMM + contraction, 64 CSR edges/block (R7-proven) ----------------
__global__ __launch_bounds__(256) void k_edge(
  const float* __restrict__ atom, const int* __restrict__ bidx, const float* __restrict__ bond,
  const unsigned short* __restrict__ Bh, const unsigned short* __restrict__ Bl,
  const int* __restrict__ elist, float* __restrict__ nbC)
{
  __shared__ float sA[4352];    // atomT [d(64)][stride 68]
  __shared__ float sP[8192];    // wave partials
  __shared__ int   sEl[64];
  __shared__ int   sNbr[64];

  int tid = threadIdx.x;
  int l = tid & 63;
  int w = tid >> 6;
  int g = l >> 5;
  int em = l & 31;
  int E0 = blockIdx.x * 64;

  if (tid < 64){
    int e = elist[E0+tid];
    sEl[tid] = e;
    sNbr[tid] = bidx[e*2+1];
  }
  __syncthreads();
  for (int i=tid; i<4096; i+=256){
    int le=i>>6, d=i&63;
    sA[d*68+le] = atom[(size_t)sNbr[le]*64 + d];
  }

  U8 A1[2], A2[2];
  #pragma unroll
  for (int mt=0; mt<2; mt++){
    const f4* bp = (const f4*)(bond + (size_t)sEl[mt*32+em]*12);
    f4 b0=bp[0], b1v=bp[1], b2v=bp[2];
    float bv[12] = {b0.x,b0.y,b0.z,b0.w,b1v.x,b1v.y,b1v.z,b1v.w,b2v.x,b2v.y,b2v.z,b2v.w};
    unsigned short hi[12], lo2[12];
    #pragma unroll
    for (int j=0;j<12;j++){ hi[j]=bf_rne(bv[j]); lo2[j]=bf_rne(bv[j]-bf_to_f(hi[j])); }
    #pragma unroll
    for (int j=0;j<8;j++){
      int k = g*8+j;
      A1[mt].us[j] = (k<12)? hi[k] : (k==12? (unsigned short)0x3F80 : (unsigned short)0);
      A2[mt].us[j] = (k<12)? lo2[k] : (unsigned short)0;
    }
  }
  __syncthreads();

  f4 nacc[2][2][4];   // [mt][ft][q]
  #pragma unroll
  for (int mt=0; mt<2; mt++)
    #pragma unroll
    for (int ft=0; ft<2; ft++)
      #pragma unroll
      for (int q=0;q<4;q++) nacc[mt][ft][q] = (f4){0.f,0.f,0.f,0.f};
  f16v cz;
  #pragma unroll
  for (int r=0;r<16;r++) cz[r] = 0.f;

  int dbase = w*16;
  U8 cbh0, cbl0, cbh1, cbl1;
  cbh0.v = *(const bf16x8*)(Bh + ((size_t)((dbase*2+0)*64 + l))*8);
  cbl0.v = *(const bf16x8*)(Bl + ((size_t)((dbase*2+0)*64 + l))*8);
  cbh1.v = *(const bf16x8*)(Bh + ((size_t)((dbase*2+1)*64 + l))*8);
  cbl1.v = *(const bf16x8*)(Bl + ((size_t)((dbase*2+1)*64 + l))*8);

  #pragma unroll 2
  for (int dd=0; dd<16; dd++){
    int d = dbase + dd;
    int dn = (dd<15)? d+1 : d;
    U8 nbh0, nbl0, nbh1, nbl1;
    nbh0.v = *(const bf16x8*)(Bh + ((size_t)((dn*2+0)*64 + l))*8);
    nbl0.v = *(const bf16x8*)(Bl + ((size_t)((dn*2+0)*64 + l))*8);
    nbh1.v = *(const bf16x8*)(Bh + ((size_t)((dn*2+1)*64 + l))*8);
    nbl1.v = *(const bf16x8*)(Bl + ((size_t)((dn*2+1)*64 + l))*8);

    #pragma unroll
    for (int mt=0; mt<2; mt++){
      f4 ldA[4];
      #pragma unroll
      for (int q=0;q<4;q++) ldA[q] = *(const f4*)&sA[d*68 + mt*32 + 8*q + 4*g];
      {
        f16v c;
        c = __builtin_amdgcn_mfma_f32_32x32x16_bf16(A1[mt].v, cbh0.v, cz, 0,0,0);
        c = __builtin_amdgcn_mfma_f32_32x32x16_bf16(A2[mt].v, cbh0.v, c, 0,0,0);
        c = __builtin_amdgcn_mfma_f32_32x32x16_bf16(A1[mt].v, cbl0.v, c, 0,0,0);
        #pragma unroll
        for (int r=0;r<16;r++){
          float ev = fmaxf(c[r], 0.f);
          nacc[mt][0][r>>2][r&3] = fmaf(ldA[r>>2][r&3], ev, nacc[mt][0][r>>2][r&3]);
        }
      }
      {
        f16v c;
        c = __builtin_amdgcn_mfma_f32_32x32x16_bf16(A1[mt].v, cbh1.v, cz, 0,0,0);
        c = __builtin_amdgcn_mfma_f32_32x32x16_bf16(A2[mt].v, cbh1.v, c, 0,0,0);
        c = __builtin_amdgcn_mfma_f32_32x32x16_bf16(A1[mt].v, cbl1.v, c, 0,0,0);
        #pragma unroll
        for (int r=0;r<16;r++){
          float ev = fmaxf(c[r], 0.f);
          nacc[mt][1][r>>2][r&3] = fmaf(ldA[r>>2][r&3], ev, nacc[mt][1][r>>2][r&3]);
        }
      }
    }
    cbh0 = nbh0; cbl0 = nbl0; cbh1 = nbh1; cbl1 = nbl1;
  }

  // two ft rounds: dump wave partials, reduce across 4 waves, write nbC (CSR order)
  #pragma unroll
  for (int ft=0; ft<2; ft++){
    __syncthreads();
    #pragma unroll
    for (int mt=0; mt<2; mt++)
      #pragma unroll
      for (int r=0;r<16;r++)
        sP[w*2048 + mt*1024 + r*64 + l] = nacc[mt][ft][r>>2][r&3];
    __syncthreads();
    for (int idx=tid; idx<2048; idx+=256){
      float v = sP[idx] + sP[2048+idx] + sP[4096+idx] + sP[6144+idx];
      int mt = idx>>10, rl = idx&1023;
      int r = rl>>6, ll = rl&63;
      int m = mt*32 + (r&3) + ((r>>2)<<3) + ((ll>>5)<<2);
      int f = (ft<<5) + (ll&31);
      nbC[(size_t)(E0+m)*64 + f] = v;
    }
  }
}

// ---------------- k_zq: qv + attd MFMA over one 64-edge tile (in-place: zC aliases nbC) ----------------
__global__ __launch_bounds__(256) void k_zq(
  const float* __restrict__ nbC,
  const unsigned short* __restrict__ aBh, const unsigned short* __restrict__ aBl,
  const float* __restrict__ alW,
  float* __restrict__ zC, float* __restrict__ qv)
{
  __shared__ float sNb[64*68];
  int tid = threadIdx.x;
  int l = tid & 63;
  int w = tid >> 6;
  int g = l >> 5;
  int em = l & 31;
  int E0 = blockIdx.x * 64;

  // coalesced tile load (entire tile staged BEFORE any overwrite)
  for (int i=tid; i<4096; i+=256){
    int le=i>>6, f=i&63;
    sNb[le*68+f] = nbC[(size_t)(E0+le)*64 + f];
  }
  __syncthreads();

  // qv[e] = alW[64:128] . nb_e  (wave w: 16 edges)
  {
    float alwn = alW[64+l];
    #pragma unroll 4
    for (int i=0;i<16;i++){
      int le = w*16 + i;
      float qq = sNb[le*68 + l] * alwn;
      qq += __shfl_xor(qq,1);  qq += __shfl_xor(qq,2);
      qq += __shfl_xor(qq,4);  qq += __shfl_xor(qq,8);
      qq += __shfl_xor(qq,16); qq += __shfl_xor(qq,32);
      if (l==0) qv[E0+le] = qq;
    }
  }

  // attd MFMA: z = nb @ attW_fold (hi/lo), wave w -> (mt2 = w>>1, nt = w&1)
  {
    f16v c;
    #pragma unroll
    for (int r=0;r<16;r++) c[r] = 0.f;
    int mt2 = w>>1, nt = w&1;
    #pragma unroll
    for (int kk=0; kk<4; kk++){
      const float* src = &sNb[(mt2*32+em)*68 + kk*16 + g*8];
      f4 x0 = *(const f4*)src;
      f4 x1 = *(const f4*)(src+4);
      U8 Ah, Al;
      #pragma unroll
      for (int j=0;j<4;j++){
        unsigned short h0 = bf_rne(x0[j]);
        Ah.us[j] = h0; Al.us[j] = bf_rne(x0[j]-bf_to_f(h0));
        unsigned short h1 = bf_rne(x1[j]);
        Ah.us[4+j] = h1; Al.us[4+j] = bf_rne(x1[j]-bf_to_f(h1));
      }
      U8 bh, bl;
      bh.v = *(const bf16x8*)(aBh + ((size_t)((kk*2+nt)*64 + l))*8);
      bl.v = *(const bf16x8*)(aBl + ((size_t)((kk*2+nt)*64 + l))*8);
      c = __builtin_amdgcn_mfma_f32_32x32x16_bf16(Ah.v, bh.v, c, 0,0,0);
      c = __builtin_amdgcn_mfma_f32_32x32x16_bf16(Al.v, bh.v, c, 0,0,0);
      c = __builtin_amdgcn_mfma_f32_32x32x16_bf16(Ah.v, bl.v, c, 0,0,0);
    }
    // wait until ALL waves finished reading sNb before global overwrite is irrelevant:
    // zC writes go to global (aliasing nbC), but every wave read ONLY from LDS copy.
    #pragma unroll
    for (int r=0;r<16;r++){
      int row = (r&3) + ((r>>2)<<3) + ((l>>5)<<2);
      zC[(size_t)(E0 + mt2*32 + row)*64 + nt*32 + (l&31)] = c[r];
    }
  }
}

// ---------------- k_gru: scalar softmax + z-combine + ELU + GRU (8 atoms/block) ----------------
__global__ __launch_bounds__(256) void k_gru(
  const float* __restrict__ atom, const float* __restrict__ zC,
  const int* __restrict__ rowstart, const float* __restrict__ p,
  const float* __restrict__ qv, const float* __restrict__ alB,
  const float* __restrict__ attBf, const float* __restrict__ wT,
  const float* __restrict__ bih, const float* __restrict__ bhh,
  float* __restrict__ out)
{
  __shared__ float sc[4][2][64];
  __shared__ float shh[4][2][64];
  int tid = threadIdx.x;
  int l = tid & 63;
  int w = tid >> 6;
  int base = blockIdx.x*8 + w*2;
  float bias = attBf[l];
  float ab = alB[0];

  #pragma unroll
  for (int aa=0; aa<2; aa++){
    int a = base + aa;
    float cf=0.f, hf=0.f;
    if (a < NA){
      hf = atom[(size_t)a*64 + l];
      int d0 = rowstart[a];
      int deg = rowstart[a+1] - d0;
      if (deg > 0){
        float pa = p[a] + ab;
        float mx = -1e30f;
        for (int i=0;i<deg;i++){
          float s = pa + qv[d0+i];
          s = (s>0.f)? s : 0.01f*s;
          mx = fmaxf(mx, s);
        }
        float dn = 0.f, y = 0.f;
        for (int i=0;i<deg;i++){
          float s = pa + qv[d0+i];
          s = (s>0.f)? s : 0.01f*s;
          float ex = __expf(s - mx);
          dn += ex;
          y = fmaf(ex, zC[(size_t)(d0+i)*64 + l], y);
        }
        cf = (y + dn*bias)/(dn + 1e-8f);
        cf = (cf>0.f)? cf : expm1f(cf);
      }
    }
    sc[w][aa][l] = cf; shh[w][aa][l] = hf;
  }
  __syncthreads();

  float acc[6][2];
  #pragma unroll
  for (int gg=0;gg<6;gg++){ acc[gg][0]=0.f; acc[gg][1]=0.f; }

  for (int kg=0; kg<16; kg++){
    f4 wv[6];
    #pragma unroll
    for (int gg=0;gg<6;gg++) wv[gg] = *(const f4*)&wT[(size_t)((gg*16+kg)*64 + l)*4];
    #pragma unroll
    for (int aa=0;aa<2;aa++){
      f4 cv = *(const f4*)&sc[w][aa][kg*4];
      f4 hv = *(const f4*)&shh[w][aa][kg*4];
      #pragma unroll
      for (int j=0;j<4;j++){
        acc[0][aa] = fmaf(cv[j], wv[0][j], acc[0][aa]);
        acc[1][aa] = fmaf(cv[j], wv[1][j], acc[1][aa]);
        acc[2][aa] = fmaf(cv[j], wv[2][j], acc[2][aa]);
        acc[3][aa] = fmaf(hv[j], wv[3][j], acc[3][aa]);
        acc[4][aa] = fmaf(hv[j], wv[4][j], acc[4][aa]);
        acc[5][aa] = fmaf(hv[j], wv[5][j], acc[5][aa]);
      }
    }
  }

  float b0 = bih[l], b1 = bih[64+l], b2 = bih[128+l];
  float h0 = bhh[l], h1 = bhh[64+l], h2 = bhh[128+l];
  #pragma unroll
  for (int aa=0;aa<2;aa++){
    int a = base + aa;
    if (a < NA){
      float hf = shh[w][aa][l];
      float r = 1.f/(1.f + expf(-(acc[0][aa] + b0 + acc[3][aa] + h0)));
      float z = 1.f/(1.f + expf(-(acc[1][aa] + b1 + acc[4][aa] + h1)));
      float n = tanhf(acc[2][aa] + b2 + r*(acc[5][aa] + h2));
      out[(size_t)a*64 + l] = (1.f - z)*n + z*hf;
    }
  }
}

extern "C" void kernel_launch(void* const* d_in, const int* in_sizes, int n_in,
                              void* d_out, int out_size, void* d_ws, size_t ws_size,
                              hipStream_t stream) {
  const float* atom = (const float*)d_in[0];
  const int*   bidx = (const int*)  d_in[1];
  const float* bond = (const float*)d_in[2];
  const float* encW = (const float*)d_in[3];
  const float* encB = (const float*)d_in[4];
  const float* eg   = (const float*)d_in[5];
  const float* ebt  = (const float*)d_in[6];
  const float* e_mn = (const float*)d_in[7];
  const float* e_vr = (const float*)d_in[8];
  const float* alW  = (const float*)d_in[9];
  const float* alB  = (const float*)d_in[10];
  const float* atW  = (const float*)d_in[11];
  const float* atB  = (const float*)d_in[12];
  const float* agm  = (const float*)d_in[13];
  const float* abt  = (const float*)d_in[14];
  const float* amn  = (const float*)d_in[15];
  const float* avr  = (const float*)d_in[16];
  const float* wih  = (const float*)d_in[17];
  const float* whh  = (const float*)d_in[18];
  const float* bih  = (const float*)d_in[19];
  const float* bhh  = (const float*)d_in[20];

  float* ws = (float*)d_ws;
  unsigned short* Bh  = (unsigned short*)(ws + 0);      // 65536 ush
  unsigned short* Bl  = (unsigned short*)(ws + 32768);  // 65536 ush
  unsigned short* aBh = (unsigned short*)(ws + 65536);  // 4096 ush
  unsigned short* aBl = (unsigned short*)(ws + 67584);  // 4096 ush
  float* attBf   = ws + 69632;    // 64
  float* wT      = ws + 69696;    // 24576
  float* p       = ws + 94272;    // 10016
  int*   cnt     = (int*)(ws + 104288);   // 10016
  int*   rowstart= (int*)(ws + 114304);   // 10016
  int*   wofs    = (int*)(ws + 124320);   // 10016
  int*   elist   = (int*)(ws + 134336);   // 40000
  float* qv      = ws + 174336;   // 40000
  float* nbC     = ws + 214336;   // 2560000 (zC aliases this, in-place)
  float* outp    = (float*)d_out;

  hipMemsetAsync(cnt, 0, NA*sizeof(int), stream);
  k_pre<<<512, 256, 0, stream>>>(encW,encB,eg,ebt,e_mn,e_vr,
                                 atW,atB,agm,abt,amn,avr,
                                 wih,whh,bidx,atom,alW,
                                 Bh,Bl,aBh,aBl,attBf,wT,p,cnt);
  k_scan<<<1, 256, 0, stream>>>(cnt, rowstart, wofs);
  k_scatter<<<(NE+255)/256, 256, 0, stream>>>(bidx, wofs, elist);
  k_edge<<<625, 256, 0, stream>>>(atom, bidx, bond, Bh, Bl, elist, nbC);
  k_zq<<<625, 256, 0, stream>>>(nbC, aBh, aBl, alW, nbC /*in-place zC*/, qv);
  k_gru<<<1250, 256, 0, stream>>>(atom, nbC, rowstart, p, qv, alB,
                                  attBf, wT, bih, bhh, outp);
}

// Round 10
// 187.991 us; speedup vs baseline: 1.7463x; 1.7463x over previous
//
#include <hip/hip_runtime.h>
#include <math.h>

#define NA 10000
#define NE 40000

typedef float f4 __attribute__((ext_vector_type(4)));
typedef float f16v __attribute__((ext_vector_type(16)));
typedef int   i4 __attribute__((ext_vector_type(4)));
typedef __bf16 bf16x8 __attribute__((ext_vector_type(8)));

union U8 { unsigned short us[8]; bf16x8 v; };

static __device__ __forceinline__ unsigned short bf_rne(float x){
  unsigned u = __float_as_uint(x);
  unsigned r = (u + 0x7fffu + ((u>>16)&1u)) >> 16;
  return (unsigned short)r;
}
static __device__ __forceinline__ float bf_to_f(unsigned short h){
  return __uint_as_float(((unsigned)h)<<16);
}

// ---------------- k_pre: fold BN, build MFMA tables, p[a], histogram ----------------
__global__ __launch_bounds__(256) void k_pre(
  const float* __restrict__ encW, const float* __restrict__ encB,
  const float* __restrict__ eg, const float* __restrict__ ebt,
  const float* __restrict__ e_mn, const float* __restrict__ e_vr,
  const float* __restrict__ attW, const float* __restrict__ attB,
  const float* __restrict__ agm, const float* __restrict__ abt,
  const float* __restrict__ amn, const float* __restrict__ avr,
  const float* __restrict__ wih, const float* __restrict__ whh,
  const int* __restrict__ bidx, const float* __restrict__ atom,
  const float* __restrict__ alW,
  unsigned short* __restrict__ Bh, unsigned short* __restrict__ Bl,
  unsigned short* __restrict__ aBh, unsigned short* __restrict__ aBl,
  float* __restrict__ attBf, float* __restrict__ wT,
  float* __restrict__ p, int* __restrict__ cnt)
{
  int tid = threadIdx.x;
  int gid = blockIdx.x*256 + tid;
  int gstride = gridDim.x*256;
  // enc B-fragments [d(64)][ft(2)][lane(64)][j(8)]
  for (int i=gid; i<65536; i+=gstride){
    int j = i&7, ll = (i>>3)&63, t = i>>9;
    int d = t>>1, ft = t&1;
    int k = ((ll>>5)<<3)+j;
    int n = d*64 + ft*32 + (ll&31);
    float s = eg[n]*rsqrtf(e_vr[n]+1e-6f);
    unsigned short vh=0, vl=0;
    if (k<12){
      float wv = encW[n*12+k]*s;
      unsigned short hi = bf_rne(wv);
      vh = hi; vl = bf_rne(wv - bf_to_f(hi));
    } else if (k==12){
      float b = (encB[n]-e_mn[n])*s + ebt[n];
      unsigned short hi = bf_rne(b);
      vh = hi; vl = bf_rne(b - bf_to_f(hi));
    }
    Bh[i] = vh; Bl[i] = vl;
  }
  // attd B-fragments [kk(4)][nt(2)][lane(64)][j(8)]; B[k][n] = attW[n*64+k]*s_n
  for (int i=gid; i<4096; i+=gstride){
    int j=i&7, l=(i>>3)&63, t=i>>9;
    int kk=t>>1, nt=t&1;
    int k = kk*16 + ((l>>5)<<3) + j;
    int n = nt*32 + (l&31);
    float s = agm[n]*rsqrtf(avr[n]+1e-6f);
    float wv = attW[n*64+k]*s;
    unsigned short hi = bf_rne(wv);
    aBh[i]=hi; aBl[i]=bf_rne(wv - bf_to_f(hi));
  }
  for (int f=gid; f<64; f+=gstride){
    float s = agm[f]*rsqrtf(avr[f]+1e-6f);
    attBf[f] = (attB[f]-amn[f])*s + abt[f];
  }
  // GRU weights [g(6)][kg(16)][f(64)][j(4)]
  for (int i=gid; i<24576; i+=gstride){
    int j=i&3, f=(i>>2)&63, idx2=i>>8;
    int g=idx2>>4, kg=idx2&15, k=kg*4+j;
    wT[i] = (g<3)? wih[(g*64+f)*64+k] : whh[((g-3)*64+f)*64+k];
  }
  // p[a] = alW[0:64] . atom[a]
  {
    int wid = gid>>6;
    int l = tid&63;
    float wl = alW[l];
    for (int a=wid; a<NA; a+=(gstride>>6)){
      float v = wl*atom[(size_t)a*64+l];
      v += __shfl_xor(v,1);  v += __shfl_xor(v,2);
      v += __shfl_xor(v,4);  v += __shfl_xor(v,8);
      v += __shfl_xor(v,16); v += __shfl_xor(v,32);
      if (l==0) p[a]=v;
    }
  }
  for (int e=gid; e<NE; e+=gstride) atomicAdd(&cnt[bidx[e*2]],1);
}

// ---------------- k_scan ----------------
__global__ __launch_bounds__(256) void k_scan(const int* __restrict__ cnt,
                                              int* __restrict__ rowstart,
                                              int* __restrict__ wofs)
{
  __shared__ int sPart[256];
  int t = threadIdx.x;
  int base = t*40;
  i4 buf[10];
  int sum = 0;
  if (base < NA){
    const i4* cp = (const i4*)(cnt + base);
    #pragma unroll
    for (int i=0;i<10;i++) buf[i] = cp[i];
    #pragma unroll
    for (int i=0;i<10;i++) sum += buf[i].x+buf[i].y+buf[i].z+buf[i].w;
  }
  sPart[t]=sum;
  __syncthreads();
  for (int off=1; off<256; off<<=1){
    int v = (t>=off)? sPart[t-off] : 0;
    __syncthreads();
    sPart[t]+=v;
    __syncthreads();
  }
  int run = sPart[t]-sum;
  if (base < NA){
    #pragma unroll
    for (int i=0;i<10;i++){
      i4 b=buf[i], o;
      o.x=run; run+=b.x; o.y=run; run+=b.y;
      o.z=run; run+=b.z; o.w=run; run+=b.w;
      ((i4*)(rowstart+base))[i]=o;
      ((i4*)(wofs+base))[i]=o;
    }
  }
  if (t==0) rowstart[NA]=NE;
}

// ---------------- k_scatter ----------------
__global__ __launch_bounds__(256) void k_scatter(const int* __restrict__ bidx,
                                                 int* __restrict__ wofs,
                                                 int* __restrict__ elist)
{
  int e = blockIdx.x*256 + threadIdx.x;
  if (e < NE){
    int tg = bidx[e*2];
    int pos = atomicAdd(&wofs[tg],1);
    elist[pos]=e;
  }
}

// ---------------- k_edge: MFMA enc GEMM + contraction, 64 CSR edges/block (R7-proven) ----------------
__global__ __launch_bounds__(256) void k_edge(
  const float* __restrict__ atom, const int* __restrict__ bidx, const float* __restrict__ bond,
  const unsigned short* __restrict__ Bh, const unsigned short* __restrict__ Bl,
  const int* __restrict__ elist, float* __restrict__ nbC)
{
  __shared__ float sA[4352];    // atomT [d(64)][stride 68]
  __shared__ float sP[8192];    // wave partials
  __shared__ int   sEl[64];
  __shared__ int   sNbr[64];

  int tid = threadIdx.x;
  int l = tid & 63;
  int w = tid >> 6;
  int g = l >> 5;
  int em = l & 31;
  int E0 = blockIdx.x * 64;

  if (tid < 64){
    int e = elist[E0+tid];
    sEl[tid] = e;
    sNbr[tid] = bidx[e*2+1];
  }
  __syncthreads();
  for (int i=tid; i<4096; i+=256){
    int le=i>>6, d=i&63;
    sA[d*68+le] = atom[(size_t)sNbr[le]*64 + d];
  }

  U8 A1[2], A2[2];
  #pragma unroll
  for (int mt=0; mt<2; mt++){
    const f4* bp = (const f4*)(bond + (size_t)sEl[mt*32+em]*12);
    f4 b0=bp[0], b1v=bp[1], b2v=bp[2];
    float bv[12] = {b0.x,b0.y,b0.z,b0.w,b1v.x,b1v.y,b1v.z,b1v.w,b2v.x,b2v.y,b2v.z,b2v.w};
    unsigned short hi[12], lo2[12];
    #pragma unroll
    for (int j=0;j<12;j++){ hi[j]=bf_rne(bv[j]); lo2[j]=bf_rne(bv[j]-bf_to_f(hi[j])); }
    #pragma unroll
    for (int j=0;j<8;j++){
      int k = g*8+j;
      A1[mt].us[j] = (k<12)? hi[k] : (k==12? (unsigned short)0x3F80 : (unsigned short)0);
      A2[mt].us[j] = (k<12)? lo2[k] : (unsigned short)0;
    }
  }
  __syncthreads();

  f4 nacc[2][2][4];   // [mt][ft][q]
  #pragma unroll
  for (int mt=0; mt<2; mt++)
    #pragma unroll
    for (int ft=0; ft<2; ft++)
      #pragma unroll
      for (int q=0;q<4;q++) nacc[mt][ft][q] = (f4){0.f,0.f,0.f,0.f};
  f16v cz;
  #pragma unroll
  for (int r=0;r<16;r++) cz[r] = 0.f;

  int dbase = w*16;
  U8 cbh0, cbl0, cbh1, cbl1;
  cbh0.v = *(const bf16x8*)(Bh + ((size_t)((dbase*2+0)*64 + l))*8);
  cbl0.v = *(const bf16x8*)(Bl + ((size_t)((dbase*2+0)*64 + l))*8);
  cbh1.v = *(const bf16x8*)(Bh + ((size_t)((dbase*2+1)*64 + l))*8);
  cbl1.v = *(const bf16x8*)(Bl + ((size_t)((dbase*2+1)*64 + l))*8);

  #pragma unroll 2
  for (int dd=0; dd<16; dd++){
    int d = dbase + dd;
    int dn = (dd<15)? d+1 : d;
    U8 nbh0, nbl0, nbh1, nbl1;
    nbh0.v = *(const bf16x8*)(Bh + ((size_t)((dn*2+0)*64 + l))*8);
    nbl0.v = *(const bf16x8*)(Bl + ((size_t)((dn*2+0)*64 + l))*8);
    nbh1.v = *(const bf16x8*)(Bh + ((size_t)((dn*2+1)*64 + l))*8);
    nbl1.v = *(const bf16x8*)(Bl + ((size_t)((dn*2+1)*64 + l))*8);

    #pragma unroll
    for (int mt=0; mt<2; mt++){
      f4 ldA[4];
      #pragma unroll
      for (int q=0;q<4;q++) ldA[q] = *(const f4*)&sA[d*68 + mt*32 + 8*q + 4*g];
      {
        f16v c;
        c = __builtin_amdgcn_mfma_f32_32x32x16_bf16(A1[mt].v, cbh0.v, cz, 0,0,0);
        c = __builtin_amdgcn_mfma_f32_32x32x16_bf16(A2[mt].v, cbh0.v, c, 0,0,0);
        c = __builtin_amdgcn_mfma_f32_32x32x16_bf16(A1[mt].v, cbl0.v, c, 0,0,0);
        #pragma unroll
        for (int r=0;r<16;r++){
          float ev = fmaxf(c[r], 0.f);
          nacc[mt][0][r>>2][r&3] = fmaf(ldA[r>>2][r&3], ev, nacc[mt][0][r>>2][r&3]);
        }
      }
      {
        f16v c;
        c = __builtin_amdgcn_mfma_f32_32x32x16_bf16(A1[mt].v, cbh1.v, cz, 0,0,0);
        c = __builtin_amdgcn_mfma_f32_32x32x16_bf16(A2[mt].v, cbh1.v, c, 0,0,0);
        c = __builtin_amdgcn_mfma_f32_32x32x16_bf16(A1[mt].v, cbl1.v, c, 0,0,0);
        #pragma unroll
        for (int r=0;r<16;r++){
          float ev = fmaxf(c[r], 0.f);
          nacc[mt][1][r>>2][r&3] = fmaf(ldA[r>>2][r&3], ev, nacc[mt][1][r>>2][r&3]);
        }
      }
    }
    cbh0 = nbh0; cbl0 = nbl0; cbh1 = nbh1; cbl1 = nbl1;
  }

  // two ft rounds: dump wave partials, reduce across 4 waves, write nbC (CSR order)
  #pragma unroll
  for (int ft=0; ft<2; ft++){
    __syncthreads();
    #pragma unroll
    for (int mt=0; mt<2; mt++)
      #pragma unroll
      for (int r=0;r<16;r++)
        sP[w*2048 + mt*1024 + r*64 + l] = nacc[mt][ft][r>>2][r&3];
    __syncthreads();
    for (int idx=tid; idx<2048; idx+=256){
      float v = sP[idx] + sP[2048+idx] + sP[4096+idx] + sP[6144+idx];
      int mt = idx>>10, rl = idx&1023;
      int r = rl>>6, ll = rl&63;
      int m = mt*32 + (r&3) + ((r>>2)<<3) + ((ll>>5)<<2);
      int f = (ft<<5) + (ll&31);
      nbC[(size_t)(E0+m)*64 + f] = v;
    }
  }
}

// ---------------- k_zq: qv + attd MFMA over one 64-edge tile (in-place: zC aliases nbC) ----------------
__global__ __launch_bounds__(256) void k_zq(
  const float* __restrict__ nbC,
  const unsigned short* __restrict__ aBh, const unsigned short* __restrict__ aBl,
  const float* __restrict__ alW,
  float* __restrict__ zC, float* __restrict__ qv)
{
  __shared__ float sNb[64*68];
  int tid = threadIdx.x;
  int l = tid & 63;
  int w = tid >> 6;
  int g = l >> 5;
  int em = l & 31;
  int E0 = blockIdx.x * 64;

  // coalesced tile load (entire tile staged BEFORE any overwrite)
  for (int i=tid; i<4096; i+=256){
    int le=i>>6, f=i&63;
    sNb[le*68+f] = nbC[(size_t)(E0+le)*64 + f];
  }
  __syncthreads();

  // qv[e] = alW[64:128] . nb_e  (wave w: 16 edges)
  {
    float alwn = alW[64+l];
    #pragma unroll 4
    for (int i=0;i<16;i++){
      int le = w*16 + i;
      float qq = sNb[le*68 + l] * alwn;
      qq += __shfl_xor(qq,1);  qq += __shfl_xor(qq,2);
      qq += __shfl_xor(qq,4);  qq += __shfl_xor(qq,8);
      qq += __shfl_xor(qq,16); qq += __shfl_xor(qq,32);
      if (l==0) qv[E0+le] = qq;
    }
  }

  // attd MFMA: z = nb @ attW_fold (hi/lo), wave w -> (mt2 = w>>1, nt = w&1)
  {
    f16v c;
    #pragma unroll
    for (int r=0;r<16;r++) c[r] = 0.f;
    int mt2 = w>>1, nt = w&1;
    #pragma unroll
    for (int kk=0; kk<4; kk++){
      const float* src = &sNb[(mt2*32+em)*68 + kk*16 + g*8];
      f4 x0 = *(const f4*)src;
      f4 x1 = *(const f4*)(src+4);
      U8 Ah, Al;
      #pragma unroll
      for (int j=0;j<4;j++){
        unsigned short h0 = bf_rne(x0[j]);
        Ah.us[j] = h0; Al.us[j] = bf_rne(x0[j]-bf_to_f(h0));
        unsigned short h1 = bf_rne(x1[j]);
        Ah.us[4+j] = h1; Al.us[4+j] = bf_rne(x1[j]-bf_to_f(h1));
      }
      U8 bh, bl;
      bh.v = *(const bf16x8*)(aBh + ((size_t)((kk*2+nt)*64 + l))*8);
      bl.v = *(const bf16x8*)(aBl + ((size_t)((kk*2+nt)*64 + l))*8);
      c = __builtin_amdgcn_mfma_f32_32x32x16_bf16(Ah.v, bh.v, c, 0,0,0);
      c = __builtin_amdgcn_mfma_f32_32x32x16_bf16(Al.v, bh.v, c, 0,0,0);
      c = __builtin_amdgcn_mfma_f32_32x32x16_bf16(Ah.v, bl.v, c, 0,0,0);
    }
    #pragma unroll
    for (int r=0;r<16;r++){
      int row = (r&3) + ((r>>2)<<3) + ((l>>5)<<2);
      zC[(size_t)(E0 + mt2*32 + row)*64 + nt*32 + (l&31)] = c[r];
    }
  }
}

// ---------------- k_gru: scalar softmax + z-combine + ELU + GRU (8 atoms/block) ----------------
// __launch_bounds__(256,4): cap VGPR at 128 — R9's build spilled at 256 VGPR
// (124+194 MB scratch traffic, 172 us). unroll 2 bounds hoisted wT loads.
__global__ __launch_bounds__(256, 4) void k_gru(
  const float* __restrict__ atom, const float* __restrict__ zC,
  const int* __restrict__ rowstart, const float* __restrict__ p,
  const float* __restrict__ qv, const float* __restrict__ alB,
  const float* __restrict__ attBf, const float* __restrict__ wT,
  const float* __restrict__ bih, const float* __restrict__ bhh,
  float* __restrict__ out)
{
  __shared__ float sc[4][2][64];
  __shared__ float shh[4][2][64];
  int tid = threadIdx.x;
  int l = tid & 63;
  int w = tid >> 6;
  int base = blockIdx.x*8 + w*2;
  float bias = attBf[l];
  float ab = alB[0];

  #pragma unroll
  for (int aa=0; aa<2; aa++){
    int a = base + aa;
    float cf=0.f, hf=0.f;
    if (a < NA){
      hf = atom[(size_t)a*64 + l];
      int d0 = rowstart[a];
      int deg = rowstart[a+1] - d0;
      if (deg > 0){
        float pa = p[a] + ab;
        float mx = -1e30f;
        #pragma unroll 1
        for (int i=0;i<deg;i++){
          float s = pa + qv[d0+i];
          s = (s>0.f)? s : 0.01f*s;
          mx = fmaxf(mx, s);
        }
        float dn = 0.f, y = 0.f;
        #pragma unroll 1
        for (int i=0;i<deg;i++){
          float s = pa + qv[d0+i];
          s = (s>0.f)? s : 0.01f*s;
          float ex = __expf(s - mx);
          dn += ex;
          y = fmaf(ex, zC[(size_t)(d0+i)*64 + l], y);
        }
        cf = (y + dn*bias)/(dn + 1e-8f);
        cf = (cf>0.f)? cf : expm1f(cf);
      }
    }
    sc[w][aa][l] = cf; shh[w][aa][l] = hf;
  }
  __syncthreads();

  float acc[6][2];
  #pragma unroll
  for (int gg=0;gg<6;gg++){ acc[gg][0]=0.f; acc[gg][1]=0.f; }

  #pragma unroll 2
  for (int kg=0; kg<16; kg++){
    f4 wv[6];
    #pragma unroll
    for (int gg=0;gg<6;gg++) wv[gg] = *(const f4*)&wT[(size_t)((gg*16+kg)*64 + l)*4];
    #pragma unroll
    for (int aa=0;aa<2;aa++){
      f4 cv = *(const f4*)&sc[w][aa][kg*4];
      f4 hv = *(const f4*)&shh[w][aa][kg*4];
      #pragma unroll
      for (int j=0;j<4;j++){
        acc[0][aa] = fmaf(cv[j], wv[0][j], acc[0][aa]);
        acc[1][aa] = fmaf(cv[j], wv[1][j], acc[1][aa]);
        acc[2][aa] = fmaf(cv[j], wv[2][j], acc[2][aa]);
        acc[3][aa] = fmaf(hv[j], wv[3][j], acc[3][aa]);
        acc[4][aa] = fmaf(hv[j], wv[4][j], acc[4][aa]);
        acc[5][aa] = fmaf(hv[j], wv[5][j], acc[5][aa]);
      }
    }
  }

  float b0 = bih[l], b1 = bih[64+l], b2 = bih[128+l];
  float h0 = bhh[l], h1 = bhh[64+l], h2 = bhh[128+l];
  #pragma unroll
  for (int aa=0;aa<2;aa++){
    int a = base + aa;
    if (a < NA){
      float hf = shh[w][aa][l];
      float r = 1.f/(1.f + expf(-(acc[0][aa] + b0 + acc[3][aa] + h0)));
      float z = 1.f/(1.f + expf(-(acc[1][aa] + b1 + acc[4][aa] + h1)));
      float n = tanhf(acc[2][aa] + b2 + r*(acc[5][aa] + h2));
      out[(size_t)a*64 + l] = (1.f - z)*n + z*hf;
    }
  }
}

extern "C" void kernel_launch(void* const* d_in, const int* in_sizes, int n_in,
                              void* d_out, int out_size, void* d_ws, size_t ws_size,
                              hipStream_t stream) {
  const float* atom = (const float*)d_in[0];
  const int*   bidx = (const int*)  d_in[1];
  const float* bond = (const float*)d_in[2];
  const float* encW = (const float*)d_in[3];
  const float* encB = (const float*)d_in[4];
  const float* eg   = (const float*)d_in[5];
  const float* ebt  = (const float*)d_in[6];
  const float* e_mn = (const float*)d_in[7];
  const float* e_vr = (const float*)d_in[8];
  const float* alW  = (const float*)d_in[9];
  const float* alB  = (const float*)d_in[10];
  const float* atW  = (const float*)d_in[11];
  const float* atB  = (const float*)d_in[12];
  const float* agm  = (const float*)d_in[13];
  const float* abt  = (const float*)d_in[14];
  const float* amn  = (const float*)d_in[15];
  const float* avr  = (const float*)d_in[16];
  const float* wih  = (const float*)d_in[17];
  const float* whh  = (const float*)d_in[18];
  const float* bih  = (const float*)d_in[19];
  const float* bhh  = (const float*)d_in[20];

  float* ws = (float*)d_ws;
  unsigned short* Bh  = (unsigned short*)(ws + 0);      // 65536 ush
  unsigned short* Bl  = (unsigned short*)(ws + 32768);  // 65536 ush
  unsigned short* aBh = (unsigned short*)(ws + 65536);  // 4096 ush
  unsigned short* aBl = (unsigned short*)(ws + 67584);  // 4096 ush
  float* attBf   = ws + 69632;    // 64
  float* wT      = ws + 69696;    // 24576
  float* p       = ws + 94272;    // 10016
  int*   cnt     = (int*)(ws + 104288);   // 10016
  int*   rowstart= (int*)(ws + 114304);   // 10016
  int*   wofs    = (int*)(ws + 124320);   // 10016
  int*   elist   = (int*)(ws + 134336);   // 40000
  float* qv      = ws + 174336;   // 40000
  float* nbC     = ws + 214336;   // 2560000 (zC aliases this, in-place)
  float* outp    = (float*)d_out;

  hipMemsetAsync(cnt, 0, NA*sizeof(int), stream);
  k_pre<<<512, 256, 0, stream>>>(encW,encB,eg,ebt,e_mn,e_vr,
                                 atW,atB,agm,abt,amn,avr,
                                 wih,whh,bidx,atom,alW,
                                 Bh,Bl,aBh,aBl,attBf,wT,p,cnt);
  k_scan<<<1, 256, 0, stream>>>(cnt, rowstart, wofs);
  k_scatter<<<(NE+255)/256, 256, 0, stream>>>(bidx, wofs, elist);
  k_edge<<<625, 256, 0, stream>>>(atom, bidx, bond, Bh, Bl, elist, nbC);
  k_zq<<<625, 256, 0, stream>>>(nbC, aBh, aBl, alW, nbC /*in-place zC*/, qv);
  k_gru<<<1250, 256, 0, stream>>>(atom, nbC, rowstart, p, qv, alB,
                                  attBf, wT, bih, bhh, outp);
}

// Round 11
// 186.570 us; speedup vs baseline: 1.7596x; 1.0076x over previous
//
#include <hip/hip_runtime.h>
#include <math.h>

#define NA 10000
#define NE 40000

typedef float f4 __attribute__((ext_vector_type(4)));
typedef float f16v __attribute__((ext_vector_type(16)));
typedef int   i4 __attribute__((ext_vector_type(4)));
typedef __bf16 bf16x8 __attribute__((ext_vector_type(8)));

union U8 { unsigned short us[8]; bf16x8 v; };

static __device__ __forceinline__ unsigned short bf_rne(float x){
  unsigned u = __float_as_uint(x);
  unsigned r = (u + 0x7fffu + ((u>>16)&1u)) >> 16;
  return (unsigned short)r;
}
static __device__ __forceinline__ float bf_to_f(unsigned short h){
  return __uint_as_float(((unsigned)h)<<16);
}

// ---------------- k_pre: fold BN, build MFMA tables, p[a], histogram ----------------
__global__ __launch_bounds__(256) void k_pre(
  const float* __restrict__ encW, const float* __restrict__ encB,
  const float* __restrict__ eg, const float* __restrict__ ebt,
  const float* __restrict__ e_mn, const float* __restrict__ e_vr,
  const float* __restrict__ attW, const float* __restrict__ attB,
  const float* __restrict__ agm, const float* __restrict__ abt,
  const float* __restrict__ amn, const float* __restrict__ avr,
  const float* __restrict__ wih, const float* __restrict__ whh,
  const int* __restrict__ bidx, const float* __restrict__ atom,
  const float* __restrict__ alW,
  unsigned short* __restrict__ Bh, unsigned short* __restrict__ Bl,
  unsigned short* __restrict__ aBh, unsigned short* __restrict__ aBl,
  float* __restrict__ attBf, float* __restrict__ wT,
  float* __restrict__ p, int* __restrict__ cnt)
{
  int tid = threadIdx.x;
  int gid = blockIdx.x*256 + tid;
  int gstride = gridDim.x*256;
  // enc B-fragments [d(64)][ft(2)][lane(64)][j(8)]
  for (int i=gid; i<65536; i+=gstride){
    int j = i&7, ll = (i>>3)&63, t = i>>9;
    int d = t>>1, ft = t&1;
    int k = ((ll>>5)<<3)+j;
    int n = d*64 + ft*32 + (ll&31);
    float s = eg[n]*rsqrtf(e_vr[n]+1e-6f);
    unsigned short vh=0, vl=0;
    if (k<12){
      float wv = encW[n*12+k]*s;
      unsigned short hi = bf_rne(wv);
      vh = hi; vl = bf_rne(wv - bf_to_f(hi));
    } else if (k==12){
      float b = (encB[n]-e_mn[n])*s + ebt[n];
      unsigned short hi = bf_rne(b);
      vh = hi; vl = bf_rne(b - bf_to_f(hi));
    }
    Bh[i] = vh; Bl[i] = vl;
  }
  // attd B-fragments [kk(4)][nt(2)][lane(64)][j(8)]; B[k][n] = attW[n*64+k]*s_n
  for (int i=gid; i<4096; i+=gstride){
    int j=i&7, l=(i>>3)&63, t=i>>9;
    int kk=t>>1, nt=t&1;
    int k = kk*16 + ((l>>5)<<3) + j;
    int n = nt*32 + (l&31);
    float s = agm[n]*rsqrtf(avr[n]+1e-6f);
    float wv = attW[n*64+k]*s;
    unsigned short hi = bf_rne(wv);
    aBh[i]=hi; aBl[i]=bf_rne(wv - bf_to_f(hi));
  }
  for (int f=gid; f<64; f+=gstride){
    float s = agm[f]*rsqrtf(avr[f]+1e-6f);
    attBf[f] = (attB[f]-amn[f])*s + abt[f];
  }
  // GRU weights [g(6)][kg(16)][f(64)][j(4)]
  for (int i=gid; i<24576; i+=gstride){
    int j=i&3, f=(i>>2)&63, idx2=i>>8;
    int g=idx2>>4, kg=idx2&15, k=kg*4+j;
    wT[i] = (g<3)? wih[(g*64+f)*64+k] : whh[((g-3)*64+f)*64+k];
  }
  // p[a] = alW[0:64] . atom[a]
  {
    int wid = gid>>6;
    int l = tid&63;
    float wl = alW[l];
    for (int a=wid; a<NA; a+=(gstride>>6)){
      float v = wl*atom[(size_t)a*64+l];
      v += __shfl_xor(v,1);  v += __shfl_xor(v,2);
      v += __shfl_xor(v,4);  v += __shfl_xor(v,8);
      v += __shfl_xor(v,16); v += __shfl_xor(v,32);
      if (l==0) p[a]=v;
    }
  }
  for (int e=gid; e<NE; e+=gstride) atomicAdd(&cnt[bidx[e*2]],1);
}

// ---------------- k_scan ----------------
__global__ __launch_bounds__(256) void k_scan(const int* __restrict__ cnt,
                                              int* __restrict__ rowstart,
                                              int* __restrict__ wofs)
{
  __shared__ int sPart[256];
  int t = threadIdx.x;
  int base = t*40;
  i4 buf[10];
  int sum = 0;
  if (base < NA){
    const i4* cp = (const i4*)(cnt + base);
    #pragma unroll
    for (int i=0;i<10;i++) buf[i] = cp[i];
    #pragma unroll
    for (int i=0;i<10;i++) sum += buf[i].x+buf[i].y+buf[i].z+buf[i].w;
  }
  sPart[t]=sum;
  __syncthreads();
  for (int off=1; off<256; off<<=1){
    int v = (t>=off)? sPart[t-off] : 0;
    __syncthreads();
    sPart[t]+=v;
    __syncthreads();
  }
  int run = sPart[t]-sum;
  if (base < NA){
    #pragma unroll
    for (int i=0;i<10;i++){
      i4 b=buf[i], o;
      o.x=run; run+=b.x; o.y=run; run+=b.y;
      o.z=run; run+=b.z; o.w=run; run+=b.w;
      ((i4*)(rowstart+base))[i]=o;
      ((i4*)(wofs+base))[i]=o;
    }
  }
  if (t==0) rowstart[NA]=NE;
}

// ---------------- k_scatter ----------------
__global__ __launch_bounds__(256) void k_scatter(const int* __restrict__ bidx,
                                                 int* __restrict__ wofs,
                                                 int* __restrict__ elist)
{
  int e = blockIdx.x*256 + threadIdx.x;
  if (e < NE){
    int tg = bidx[e*2];
    int pos = atomicAdd(&wofs[tg],1);
    elist[pos]=e;
  }
}

// ---------------- k_edge v4: 32 CSR edges/block, 1250 blocks ----------------
// wave w owns (ft = w&1, d-half = w>>1): 32d x 1ft x 3 MFMA = 96 MFMA/wave,
// one pair-reduce round. LDS ~26KB (vs 50.7KB) -> 6 blocks/CU cap; grid 1250
// gives ~4.9 blocks/CU co-resident (~61% occ cap vs R10's 17% observed).
__global__ __launch_bounds__(256) void k_edge(
  const float* __restrict__ atom, const int* __restrict__ bidx, const float* __restrict__ bond,
  const unsigned short* __restrict__ Bh, const unsigned short* __restrict__ Bl,
  const int* __restrict__ elist, float* __restrict__ nbC)
{
  __shared__ float sA[2304];    // atomT [d(64)][stride 36], 9.2KB
  __shared__ float sP[4096];    // wave partials [w][r][l], 16KB
  __shared__ int   sEl[32];
  __shared__ int   sNbr[32];

  int tid = threadIdx.x;
  int l = tid & 63;
  int w = tid >> 6;
  int g = l >> 5;
  int em = l & 31;
  int E0 = blockIdx.x * 32;     // 1250 * 32 = 40000

  if (tid < 32){
    int e = elist[E0+tid];
    sEl[tid] = e;
    sNbr[tid] = bidx[e*2+1];
  }
  __syncthreads();
  for (int i=tid; i<2048; i+=256){
    int le=i>>6, d=i&63;
    sA[d*36+le] = atom[(size_t)sNbr[le]*64 + d];
  }

  // A fragments (edge = E0+em), hi/lo split, bias slot k=12 — same for all waves
  U8 A1, A2;
  {
    const f4* bp = (const f4*)(bond + (size_t)sEl[em]*12);
    f4 b0=bp[0], b1v=bp[1], b2v=bp[2];
    float bv[12] = {b0.x,b0.y,b0.z,b0.w,b1v.x,b1v.y,b1v.z,b1v.w,b2v.x,b2v.y,b2v.z,b2v.w};
    unsigned short hi[12], lo2[12];
    #pragma unroll
    for (int j=0;j<12;j++){ hi[j]=bf_rne(bv[j]); lo2[j]=bf_rne(bv[j]-bf_to_f(hi[j])); }
    #pragma unroll
    for (int j=0;j<8;j++){
      int k = g*8+j;
      A1.us[j] = (k<12)? hi[k] : (k==12? (unsigned short)0x3F80 : (unsigned short)0);
      A2.us[j] = (k<12)? lo2[k] : (unsigned short)0;
    }
  }
  __syncthreads();

  int ft = w & 1;
  int dbase = (w >> 1) * 32;

  f4 nacc[4];
  #pragma unroll
  for (int q=0;q<4;q++) nacc[q] = (f4){0.f,0.f,0.f,0.f};
  f16v cz;
  #pragma unroll
  for (int r=0;r<16;r++) cz[r] = 0.f;

  // 1-deep prefetch of this wave's (d, ft) hi/lo fragments
  U8 cbh, cbl;
  cbh.v = *(const bf16x8*)(Bh + ((size_t)((dbase*2+ft)*64 + l))*8);
  cbl.v = *(const bf16x8*)(Bl + ((size_t)((dbase*2+ft)*64 + l))*8);

  #pragma unroll 2
  for (int dd=0; dd<32; dd++){
    int d = dbase + dd;
    int dn = (dd<31)? d+1 : d;
    U8 nbh, nbl;
    nbh.v = *(const bf16x8*)(Bh + ((size_t)((dn*2+ft)*64 + l))*8);
    nbl.v = *(const bf16x8*)(Bl + ((size_t)((dn*2+ft)*64 + l))*8);

    f4 ldA[4];
    #pragma unroll
    for (int q=0;q<4;q++) ldA[q] = *(const f4*)&sA[d*36 + 8*q + 4*g];

    f16v c;
    c = __builtin_amdgcn_mfma_f32_32x32x16_bf16(A1.v, cbh.v, cz, 0,0,0);
    c = __builtin_amdgcn_mfma_f32_32x32x16_bf16(A2.v, cbh.v, c, 0,0,0);
    c = __builtin_amdgcn_mfma_f32_32x32x16_bf16(A1.v, cbl.v, c, 0,0,0);
    #pragma unroll
    for (int r=0;r<16;r++){
      float ev = fmaxf(c[r], 0.f);
      nacc[r>>2][r&3] = fmaf(ldA[r>>2][r&3], ev, nacc[r>>2][r&3]);
    }
    cbh = nbh; cbl = nbl;
  }

  // dump wave partials; waves 0/1 reduce d-half pairs (w, w+2) and store
  #pragma unroll
  for (int r=0;r<16;r++)
    sP[w*1024 + r*64 + l] = nacc[r>>2][r&3];
  __syncthreads();

  if (w < 2){
    #pragma unroll 4
    for (int r=0;r<16;r++){
      int idx = r*64 + l;
      float v = sP[w*1024 + idx] + sP[(w+2)*1024 + idx];
      int m = (r&3) + ((r>>2)<<3) + ((l>>5)<<2);
      int f = (w<<5) + (l&31);      // wave 0 -> ft 0 cols, wave 1 -> ft 1 cols
      nbC[(size_t)(E0+m)*64 + f] = v;
    }
  }
}

// ---------------- k_zq: qv + attd MFMA over one 64-edge tile (in-place: zC aliases nbC) ----------------
__global__ __launch_bounds__(256) void k_zq(
  const float* __restrict__ nbC,
  const unsigned short* __restrict__ aBh, const unsigned short* __restrict__ aBl,
  const float* __restrict__ alW,
  float* __restrict__ zC, float* __restrict__ qv)
{
  __shared__ float sNb[64*68];
  int tid = threadIdx.x;
  int l = tid & 63;
  int w = tid >> 6;
  int g = l >> 5;
  int em = l & 31;
  int E0 = blockIdx.x * 64;

  // coalesced tile load (entire tile staged BEFORE any overwrite)
  for (int i=tid; i<4096; i+=256){
    int le=i>>6, f=i&63;
    sNb[le*68+f] = nbC[(size_t)(E0+le)*64 + f];
  }
  __syncthreads();

  // qv[e] = alW[64:128] . nb_e  (wave w: 16 edges)
  {
    float alwn = alW[64+l];
    #pragma unroll 4
    for (int i=0;i<16;i++){
      int le = w*16 + i;
      float qq = sNb[le*68 + l] * alwn;
      qq += __shfl_xor(qq,1);  qq += __shfl_xor(qq,2);
      qq += __shfl_xor(qq,4);  qq += __shfl_xor(qq,8);
      qq += __shfl_xor(qq,16); qq += __shfl_xor(qq,32);
      if (l==0) qv[E0+le] = qq;
    }
  }

  // attd MFMA: z = nb @ attW_fold (hi/lo), wave w -> (mt2 = w>>1, nt = w&1)
  {
    f16v c;
    #pragma unroll
    for (int r=0;r<16;r++) c[r] = 0.f;
    int mt2 = w>>1, nt = w&1;
    #pragma unroll
    for (int kk=0; kk<4; kk++){
      const float* src = &sNb[(mt2*32+em)*68 + kk*16 + g*8];
      f4 x0 = *(const f4*)src;
      f4 x1 = *(const f4*)(src+4);
      U8 Ah, Al;
      #pragma unroll
      for (int j=0;j<4;j++){
        unsigned short h0 = bf_rne(x0[j]);
        Ah.us[j] = h0; Al.us[j] = bf_rne(x0[j]-bf_to_f(h0));
        unsigned short h1 = bf_rne(x1[j]);
        Ah.us[4+j] = h1; Al.us[4+j] = bf_rne(x1[j]-bf_to_f(h1));
      }
      U8 bh, bl;
      bh.v = *(const bf16x8*)(aBh + ((size_t)((kk*2+nt)*64 + l))*8);
      bl.v = *(const bf16x8*)(aBl + ((size_t)((kk*2+nt)*64 + l))*8);
      c = __builtin_amdgcn_mfma_f32_32x32x16_bf16(Ah.v, bh.v, c, 0,0,0);
      c = __builtin_amdgcn_mfma_f32_32x32x16_bf16(Al.v, bh.v, c, 0,0,0);
      c = __builtin_amdgcn_mfma_f32_32x32x16_bf16(Ah.v, bl.v, c, 0,0,0);
    }
    #pragma unroll
    for (int r=0;r<16;r++){
      int row = (r&3) + ((r>>2)<<3) + ((l>>5)<<2);
      zC[(size_t)(E0 + mt2*32 + row)*64 + nt*32 + (l&31)] = c[r];
    }
  }
}

// ---------------- k_gru: scalar softmax + z-combine + ELU + GRU (8 atoms/block) ----------------
// __launch_bounds__(256,4): cap VGPR at 128 — R9's build spilled at 256 VGPR.
// unroll 2 bounds hoisted wT loads.
__global__ __launch_bounds__(256, 4) void k_gru(
  const float* __restrict__ atom, const float* __restrict__ zC,
  const int* __restrict__ rowstart, const float* __restrict__ p,
  const float* __restrict__ qv, const float* __restrict__ alB,
  const float* __restrict__ attBf, const float* __restrict__ wT,
  const float* __restrict__ bih, const float* __restrict__ bhh,
  float* __restrict__ out)
{
  __shared__ float sc[4][2][64];
  __shared__ float shh[4][2][64];
  int tid = threadIdx.x;
  int l = tid & 63;
  int w = tid >> 6;
  int base = blockIdx.x*8 + w*2;
  float bias = attBf[l];
  float ab = alB[0];

  #pragma unroll
  for (int aa=0; aa<2; aa++){
    int a = base + aa;
    float cf=0.f, hf=0.f;
    if (a < NA){
      hf = atom[(size_t)a*64 + l];
      int d0 = rowstart[a];
      int deg = rowstart[a+1] - d0;
      if (deg > 0){
        float pa = p[a] + ab;
        float mx = -1e30f;
        #pragma unroll 1
        for (int i=0;i<deg;i++){
          float s = pa + qv[d0+i];
          s = (s>0.f)? s : 0.01f*s;
          mx = fmaxf(mx, s);
        }
        float dn = 0.f, y = 0.f;
        #pragma unroll 1
        for (int i=0;i<deg;i++){
          float s = pa + qv[d0+i];
          s = (s>0.f)? s : 0.01f*s;
          float ex = __expf(s - mx);
          dn += ex;
          y = fmaf(ex, zC[(size_t)(d0+i)*64 + l], y);
        }
        cf = (y + dn*bias)/(dn + 1e-8f);
        cf = (cf>0.f)? cf : expm1f(cf);
      }
    }
    sc[w][aa][l] = cf; shh[w][aa][l] = hf;
  }
  __syncthreads();

  float acc[6][2];
  #pragma unroll
  for (int gg=0;gg<6;gg++){ acc[gg][0]=0.f; acc[gg][1]=0.f; }

  #pragma unroll 2
  for (int kg=0; kg<16; kg++){
    f4 wv[6];
    #pragma unroll
    for (int gg=0;gg<6;gg++) wv[gg] = *(const f4*)&wT[(size_t)((gg*16+kg)*64 + l)*4];
    #pragma unroll
    for (int aa=0;aa<2;aa++){
      f4 cv = *(const f4*)&sc[w][aa][kg*4];
      f4 hv = *(const f4*)&shh[w][aa][kg*4];
      #pragma unroll
      for (int j=0;j<4;j++){
        acc[0][aa] = fmaf(cv[j], wv[0][j], acc[0][aa]);
        acc[1][aa] = fmaf(cv[j], wv[1][j], acc[1][aa]);
        acc[2][aa] = fmaf(cv[j], wv[2][j], acc[2][aa]);
        acc[3][aa] = fmaf(hv[j], wv[3][j], acc[3][aa]);
        acc[4][aa] = fmaf(hv[j], wv[4][j], acc[4][aa]);
        acc[5][aa] = fmaf(hv[j], wv[5][j], acc[5][aa]);
      }
    }
  }

  float b0 = bih[l], b1 = bih[64+l], b2 = bih[128+l];
  float h0 = bhh[l], h1 = bhh[64+l], h2 = bhh[128+l];
  #pragma unroll
  for (int aa=0;aa<2;aa++){
    int a = base + aa;
    if (a < NA){
      float hf = shh[w][aa][l];
      float r = 1.f/(1.f + expf(-(acc[0][aa] + b0 + acc[3][aa] + h0)));
      float z = 1.f/(1.f + expf(-(acc[1][aa] + b1 + acc[4][aa] + h1)));
      float n = tanhf(acc[2][aa] + b2 + r*(acc[5][aa] + h2));
      out[(size_t)a*64 + l] = (1.f - z)*n + z*hf;
    }
  }
}

extern "C" void kernel_launch(void* const* d_in, const int* in_sizes, int n_in,
                              void* d_out, int out_size, void* d_ws, size_t ws_size,
                              hipStream_t stream) {
  const float* atom = (const float*)d_in[0];
  const int*   bidx = (const int*)  d_in[1];
  const float* bond = (const float*)d_in[2];
  const float* encW = (const float*)d_in[3];
  const float* encB = (const float*)d_in[4];
  const float* eg   = (const float*)d_in[5];
  const float* ebt  = (const float*)d_in[6];
  const float* e_mn = (const float*)d_in[7];
  const float* e_vr = (const float*)d_in[8];
  const float* alW  = (const float*)d_in[9];
  const float* alB  = (const float*)d_in[10];
  const float* atW  = (const float*)d_in[11];
  const float* atB  = (const float*)d_in[12];
  const float* agm  = (const float*)d_in[13];
  const float* abt  = (const float*)d_in[14];
  const float* amn  = (const float*)d_in[15];
  const float* avr  = (const float*)d_in[16];
  const float* wih  = (const float*)d_in[17];
  const float* whh  = (const float*)d_in[18];
  const float* bih  = (const float*)d_in[19];
  const float* bhh  = (const float*)d_in[20];

  float* ws = (float*)d_ws;
  unsigned short* Bh  = (unsigned short*)(ws + 0);      // 65536 ush
  unsigned short* Bl  = (unsigned short*)(ws + 32768);  // 65536 ush
  unsigned short* aBh = (unsigned short*)(ws + 65536);  // 4096 ush
  unsigned short* aBl = (unsigned short*)(ws + 67584);  // 4096 ush
  float* attBf   = ws + 69632;    // 64
  float* wT      = ws + 69696;    // 24576
  float* p       = ws + 94272;    // 10016
  int*   cnt     = (int*)(ws + 104288);   // 10016
  int*   rowstart= (int*)(ws + 114304);   // 10016
  int*   wofs    = (int*)(ws + 124320);   // 10016
  int*   elist   = (int*)(ws + 134336);   // 40000
  float* qv      = ws + 174336;   // 40000
  float* nbC     = ws + 214336;   // 2560000 (zC aliases this, in-place)
  float* outp    = (float*)d_out;

  hipMemsetAsync(cnt, 0, NA*sizeof(int), stream);
  k_pre<<<512, 256, 0, stream>>>(encW,encB,eg,ebt,e_mn,e_vr,
                                 atW,atB,agm,abt,amn,avr,
                                 wih,whh,bidx,atom,alW,
                                 Bh,Bl,aBh,aBl,attBf,wT,p,cnt);
  k_scan<<<1, 256, 0, stream>>>(cnt, rowstart, wofs);
  k_scatter<<<(NE+255)/256, 256, 0, stream>>>(bidx, wofs, elist);
  k_edge<<<1250, 256, 0, stream>>>(atom, bidx, bond, Bh, Bl, elist, nbC);
  k_zq<<<625, 256, 0, stream>>>(nbC, aBh, aBl, alW, nbC /*in-place zC*/, qv);
  k_gru<<<1250, 256, 0, stream>>>(atom, nbC, rowstart, p, qv, alB,
                                  attBf, wT, bih, bhh, outp);
}